// Round 2
// baseline (458.162 us; speedup 1.0000x reference)
//
#include <hip/hip_runtime.h>
#include <hip/hip_bf16.h>

// Problem constants (FrameSummary: B=8,T=512,K=64,D=256,P=4,KP=16)
#define ROWS   4096        // B*T
#define KTOK   64
#define DD     256
#define PP     4
#define EPS_W  1e-6f
#define LN_EPS 1e-5f

typedef __bf16 bf16_t;
typedef __attribute__((ext_vector_type(8))) __bf16 bf16x8;
typedef __attribute__((ext_vector_type(4))) float floatx4;

__device__ __forceinline__ ushort f2bf(float f) {
    union { float f; unsigned int i; } v; v.f = f;
    unsigned int r = v.i + 0x7FFFu + ((v.i >> 16) & 1u);   // RNE
    return (ushort)(r >> 16);
}

// ---------------------------------------------------------------------------
// K0: fp32 -> bf16 weight conversion (ws is re-poisoned every launch)
// ---------------------------------------------------------------------------
__global__ __launch_bounds__(256) void k_conv(const float* __restrict__ src,
                                              ushort* __restrict__ dst) {
    const int i = (blockIdx.x * 256 + threadIdx.x) * 4;
    float4 a = *reinterpret_cast<const float4*>(&src[i]);
    ushort4 o; o.x = f2bf(a.x); o.y = f2bf(a.y); o.z = f2bf(a.z); o.w = f2bf(a.w);
    *reinterpret_cast<ushort4*>(&dst[i]) = o;
}

// ---------------------------------------------------------------------------
// K1: weighted per-part pooling (fp32 in, bf16 out).
// u[row, p*256+d] = sum_j wn[p,j]*E_S[row, idx[p,j], d]
// One block per (b,t) row. 256 threads: group (tid>>6) = part, lane covers 4 dims.
// ---------------------------------------------------------------------------
__global__ __launch_bounds__(256) void k_u(const float* __restrict__ ES,
                                           const float* __restrict__ Wt,
                                           const int* __restrict__ pidx,
                                           ushort* __restrict__ u_ws) {
    __shared__ float wraw[64], wn[64], denom[4];
    __shared__ int pix[64];
    const int row = blockIdx.x;
    const int tid = threadIdx.x;
    if (tid < 64) {
        pix[tid] = pidx[tid];
        wraw[tid] = Wt[row * 64 + tid];
    }
    __syncthreads();
    if (tid < 4) {
        float s = 0.f;
        for (int j = 0; j < 16; ++j) s += wraw[pix[tid * 16 + j]];
        denom[tid] = s + EPS_W;
    }
    __syncthreads();
    if (tid < 64) wn[tid] = wraw[pix[tid]] / denom[tid >> 4];
    __syncthreads();

    const int p = tid >> 6, l = tid & 63;
    const int d0 = l * 4;
    float a0 = 0.f, a1 = 0.f, a2 = 0.f, a3 = 0.f;
    const size_t rb = (size_t)row * (KTOK * DD);
    for (int j = 0; j < 16; ++j) {
        const int k = pix[p * 16 + j];
        const float wj = wn[p * 16 + j];
        float4 t = *reinterpret_cast<const float4*>(&ES[rb + (size_t)k * DD + d0]);
        a0 += wj * t.x; a1 += wj * t.y;
        a2 += wj * t.z; a3 += wj * t.w;
    }
    ushort4 o; o.x = f2bf(a0); o.y = f2bf(a1); o.z = f2bf(a2); o.w = f2bf(a3);
    *reinterpret_cast<ushort4*>(&u_ws[(size_t)row * 1024 + p * 256 + d0]) = o;
}

// ---------------------------------------------------------------------------
// Shared MFMA mainloop: C[64 x 256] tile, A row-major [M x lda] (bf16), col
// offset acol, B stored [N=256 rows x K] bf16 (i.e. already "B^T": C = A * B^T).
// 256 threads = 4 waves; wave w owns cols [w*64, w*64+64).
// acc[mt][nt] is a 16x16 MFMA C-fragment: row=(lane>>4)*4+reg, col=lane&15.
// ---------------------------------------------------------------------------
__device__ __forceinline__ void gemm_mainloop(const ushort* __restrict__ A, int lda, int acol,
                                              const ushort* __restrict__ Bm, int ldb, int K,
                                              int m0, ushort* ldsA, ushort* ldsB,
                                              floatx4 acc[4][4]) {
    const int tid = threadIdx.x;
    const int w = tid >> 6, l = tid & 63, li = l & 15, quad = l >> 4;
    for (int k0 = 0; k0 < K; k0 += 64) {
        // stage A tile [64][64]
        for (int q = tid; q < 512; q += 256) {
            const int r = q >> 3, kc = (q & 7) * 8;
            *reinterpret_cast<uint4*>(&ldsA[r * 64 + kc]) =
                *reinterpret_cast<const uint4*>(&A[(size_t)(m0 + r) * lda + acol + k0 + kc]);
        }
        // stage B tile [256][64]
        for (int q = tid; q < 2048; q += 256) {
            const int r = q >> 3, kc = (q & 7) * 8;
            *reinterpret_cast<uint4*>(&ldsB[r * 64 + kc]) =
                *reinterpret_cast<const uint4*>(&Bm[(size_t)r * ldb + k0 + kc]);
        }
        __syncthreads();
        #pragma unroll
        for (int ks = 0; ks < 2; ++ks) {
            bf16x8 af[4], bfm[4];
            #pragma unroll
            for (int mt = 0; mt < 4; ++mt)
                af[mt] = *reinterpret_cast<const bf16x8*>(&ldsA[(mt * 16 + li) * 64 + ks * 32 + quad * 8]);
            #pragma unroll
            for (int nt = 0; nt < 4; ++nt)
                bfm[nt] = *reinterpret_cast<const bf16x8*>(&ldsB[(w * 64 + nt * 16 + li) * 64 + ks * 32 + quad * 8]);
            #pragma unroll
            for (int mt = 0; mt < 4; ++mt)
                #pragma unroll
                for (int nt = 0; nt < 4; ++nt)
                    acc[mt][nt] = __builtin_amdgcn_mfma_f32_16x16x32_bf16(af[mt], bfm[nt], acc[mt][nt], 0, 0, 0);
        }
        __syncthreads();
    }
}

// ---------------------------------------------------------------------------
// K2: per-part GEMM u_hat = u @ Wp^T + b, LN-stats -> sigmoid gate, Z = alpha*u_hat
// grid (64 row-blocks, 4 parts)
// ---------------------------------------------------------------------------
__global__ __launch_bounds__(256) void k_part(const ushort* __restrict__ u_ws,
                                              const ushort* __restrict__ partWb,
                                              const float* __restrict__ part_b,
                                              const float* __restrict__ ln_g,
                                              const float* __restrict__ ln_b,
                                              const float* __restrict__ vv,
                                              const float* __restrict__ cc,
                                              ushort* __restrict__ Z) {
    __shared__ __align__(16) ushort ldsA[64 * 64];
    __shared__ __align__(16) ushort ldsB[256 * 64];
    __shared__ float redbuf[4][64][4];
    __shared__ float alpha_s[64];
    __shared__ float gvred[4][2];
    const int m0 = blockIdx.x * 64;
    const int p = blockIdx.y;
    const int tid = threadIdx.x;
    const int w = tid >> 6, l = tid & 63, li = l & 15, quad = l >> 4;

    // block-level scalars S_gv = sum g*v, S_bv = sum b*v (over n of this part)
    {
        const int n = p * 256 + tid;
        float a = ln_g[n] * vv[n];
        float b2 = ln_b[n] * vv[n];
        for (int m = 1; m < 64; m <<= 1) { a += __shfl_xor(a, m, 64); b2 += __shfl_xor(b2, m, 64); }
        if (l == 0) { gvred[w][0] = a; gvred[w][1] = b2; }
    }

    floatx4 acc[4][4];
    #pragma unroll
    for (int mt = 0; mt < 4; ++mt)
        #pragma unroll
        for (int nt = 0; nt < 4; ++nt)
            acc[mt][nt] = (floatx4){0.f, 0.f, 0.f, 0.f};

    gemm_mainloop(u_ws, 1024, p * 256, partWb + (size_t)p * 65536, 256, 256, m0, ldsA, ldsB, acc);

    const float S_gv = gvred[0][0] + gvred[1][0] + gvred[2][0] + gvred[3][0];
    const float S_bv = gvred[0][1] + gvred[1][1] + gvred[2][1] + gvred[3][1];

    float pb[4], gv[4];
    #pragma unroll
    for (int nt = 0; nt < 4; ++nt) {
        const int n = p * 256 + w * 64 + nt * 16 + li;
        pb[nt] = part_b[n];
        gv[nt] = ln_g[n] * vv[n];
    }

    // per-row reductions: s1=sum u_hat, s2=sum u_hat^2, s3=sum u_hat*g*v
    #pragma unroll
    for (int mt = 0; mt < 4; ++mt)
        #pragma unroll
        for (int r = 0; r < 4; ++r) {
            float s1 = 0.f, s2 = 0.f, s3 = 0.f;
            #pragma unroll
            for (int nt = 0; nt < 4; ++nt) {
                float uh = acc[mt][nt][r] + pb[nt];
                acc[mt][nt][r] = uh;
                s1 += uh; s2 += uh * uh; s3 += uh * gv[nt];
            }
            for (int msk = 1; msk < 16; msk <<= 1) {
                s1 += __shfl_xor(s1, msk, 64);
                s2 += __shfl_xor(s2, msk, 64);
                s3 += __shfl_xor(s3, msk, 64);
            }
            if (li == 0) {
                const int rr = mt * 16 + quad * 4 + r;
                redbuf[w][rr][0] = s1; redbuf[w][rr][1] = s2; redbuf[w][rr][2] = s3;
            }
        }
    __syncthreads();
    if (tid < 64) {
        float t1 = 0.f, t2 = 0.f, t3 = 0.f;
        for (int ww = 0; ww < 4; ++ww) {
            t1 += redbuf[ww][tid][0]; t2 += redbuf[ww][tid][1]; t3 += redbuf[ww][tid][2];
        }
        const float mean = t1 * (1.f / 256.f);
        const float var = t2 * (1.f / 256.f) - mean * mean;
        const float rstd = rsqrtf(var + LN_EPS);
        const float arg = rstd * (t3 - mean * S_gv) + S_bv + cc[p];
        alpha_s[tid] = 1.f / (1.f + __expf(-arg));
    }
    __syncthreads();

    #pragma unroll
    for (int mt = 0; mt < 4; ++mt)
        #pragma unroll
        for (int r = 0; r < 4; ++r) {
            const int rr = mt * 16 + quad * 4 + r;
            const float al = alpha_s[rr];
            const size_t rowoff = (size_t)(m0 + rr) * 1024 + p * 256;
            #pragma unroll
            for (int nt = 0; nt < 4; ++nt) {
                const int n = w * 64 + nt * 16 + li;
                Z[rowoff + n] = f2bf(al * acc[mt][nt][r]);
            }
        }
}

// ---------------------------------------------------------------------------
// K3: S = Z @ projW^T + proj_b, then final LayerNorm -> out (fp32)
// grid 64 row-blocks
// ---------------------------------------------------------------------------
__global__ __launch_bounds__(256) void k_proj(const ushort* __restrict__ Zin,
                                              const ushort* __restrict__ projWb,
                                              const float* __restrict__ proj_b,
                                              const float* __restrict__ out_g,
                                              const float* __restrict__ out_b,
                                              float* __restrict__ out) {
    __shared__ __align__(16) ushort ldsA[64 * 64];
    __shared__ __align__(16) ushort ldsB[256 * 64];
    __shared__ float redbuf[4][64][2];
    __shared__ float stats[64][2];
    const int m0 = blockIdx.x * 64;
    const int tid = threadIdx.x;
    const int w = tid >> 6, l = tid & 63, li = l & 15, quad = l >> 4;

    floatx4 acc[4][4];
    #pragma unroll
    for (int mt = 0; mt < 4; ++mt)
        #pragma unroll
        for (int nt = 0; nt < 4; ++nt)
            acc[mt][nt] = (floatx4){0.f, 0.f, 0.f, 0.f};

    gemm_mainloop(Zin, 1024, 0, projWb, 1024, 1024, m0, ldsA, ldsB, acc);

    float pb[4], og[4], ob[4];
    #pragma unroll
    for (int nt = 0; nt < 4; ++nt) {
        const int n = w * 64 + nt * 16 + li;
        pb[nt] = proj_b[n];
        og[nt] = out_g[n];
        ob[nt] = out_b[n];
    }

    #pragma unroll
    for (int mt = 0; mt < 4; ++mt)
        #pragma unroll
        for (int r = 0; r < 4; ++r) {
            float s1 = 0.f, s2 = 0.f;
            #pragma unroll
            for (int nt = 0; nt < 4; ++nt) {
                float uh = acc[mt][nt][r] + pb[nt];
                acc[mt][nt][r] = uh;
                s1 += uh; s2 += uh * uh;
            }
            for (int msk = 1; msk < 16; msk <<= 1) {
                s1 += __shfl_xor(s1, msk, 64);
                s2 += __shfl_xor(s2, msk, 64);
            }
            if (li == 0) {
                const int rr = mt * 16 + quad * 4 + r;
                redbuf[w][rr][0] = s1; redbuf[w][rr][1] = s2;
            }
        }
    __syncthreads();
    if (tid < 64) {
        float t1 = 0.f, t2 = 0.f;
        for (int ww = 0; ww < 4; ++ww) { t1 += redbuf[ww][tid][0]; t2 += redbuf[ww][tid][1]; }
        const float mean = t1 * (1.f / 256.f);
        const float var = t2 * (1.f / 256.f) - mean * mean;
        stats[tid][0] = mean;
        stats[tid][1] = rsqrtf(var + LN_EPS);
    }
    __syncthreads();

    #pragma unroll
    for (int mt = 0; mt < 4; ++mt)
        #pragma unroll
        for (int r = 0; r < 4; ++r) {
            const int rr = mt * 16 + quad * 4 + r;
            const float mean = stats[rr][0], rstd = stats[rr][1];
            const size_t rowoff = (size_t)(m0 + rr) * 256;
            #pragma unroll
            for (int nt = 0; nt < 4; ++nt) {
                const int n = w * 64 + nt * 16 + li;
                out[rowoff + n] = (acc[mt][nt][r] - mean) * rstd * og[nt] + ob[nt];
            }
        }
}

// ---------------------------------------------------------------------------
extern "C" void kernel_launch(void* const* d_in, const int* in_sizes, int n_in,
                              void* d_out, int out_size, void* d_ws, size_t ws_size,
                              hipStream_t stream) {
    const float* ES     = (const float*)d_in[0];
    const float* W      = (const float*)d_in[1];
    const int*   pidx   = (const int*)d_in[2];
    const float* partW  = (const float*)d_in[3];
    const float* part_b = (const float*)d_in[4];
    const float* v      = (const float*)d_in[5];
    const float* c      = (const float*)d_in[6];
    const float* ln_g   = (const float*)d_in[7];
    const float* ln_b   = (const float*)d_in[8];
    const float* projW  = (const float*)d_in[9];
    const float* proj_b = (const float*)d_in[10];
    const float* out_g  = (const float*)d_in[11];
    const float* out_b  = (const float*)d_in[12];

    ushort* u_ws   = (ushort*)d_ws;                     // [4096][1024] bf16 = 8 MB
    ushort* Z      = u_ws + (size_t)ROWS * 1024;        // [4096][1024] bf16 = 8 MB
    ushort* partWb = Z + (size_t)ROWS * 1024;           // [4][256][256] bf16 = 512 KB
    ushort* projWb = partWb + (size_t)PP * DD * DD;     // [256][1024] bf16 = 512 KB
    float*  out    = (float*)d_out;                     // [4096][256] fp32

    k_conv<<<PP * DD * DD / 1024, 256, 0, stream>>>(partW, partWb);
    k_conv<<<DD * PP * DD / 1024, 256, 0, stream>>>(projW, projWb);
    k_u<<<ROWS, 256, 0, stream>>>(ES, W, pidx, u_ws);
    k_part<<<dim3(ROWS / 64, PP), 256, 0, stream>>>(u_ws, partWb, part_b, ln_g, ln_b, v, c, Z);
    k_proj<<<ROWS / 64, 256, 0, stream>>>(Z, projWb, proj_b, out_g, out_b, out);
}